// Round 12
// baseline (264.537 us; speedup 1.0000x reference)
//
#include <hip/hip_runtime.h>
#include <cstdint>
#include <cmath>

#define BDIM 256

constexpr int Bsz = 32;
constexpr int Tt  = 512;
constexpr int Nn  = 1024;
constexpr int SEG = 8;     // T split into 8 segments of 64 for the scan (R8)
constexpr int SLEN = 64;
constexpr int SPLITS = 16; // R18: split-K 16 (atomics freed the partials ws)
constexpr int NKT = (2 * Bsz * Tt / 32) / SPLITS;  // 64 ktiles per split
constexpr float A_PLUS  = 0.005f;
constexpr float A_MINUS = 0.00525f;
constexpr float A_TP    = 0.0001f;
constexpr float A_TM    = 0.0001f;

typedef __attribute__((ext_vector_type(8))) short short8;   // 8 bf16 = 4 VGPRs
typedef __attribute__((ext_vector_type(4))) float float4v;  // MFMA acc

__device__ __forceinline__ unsigned short f2bf(float f) {
  // round-to-nearest-even fp32 -> bf16 (values are finite)
  unsigned u = __float_as_uint(f);
  u += 0x7fffu + ((u >> 16) & 1u);
  return (unsigned short)(u >> 16);
}

// ---------------------------------------------------------------------------
// Phase 1: trace recurrences -> bf16 operands. FROZEN at R14 (passed 5
// rounds at 80-82us). R9-R16 established Phase-B is not profitably
// attackable; kernel is phase-structure-bound at ~2.5 blocks/CU.
// ---------------------------------------------------------------------------
__global__ __launch_bounds__(BDIM, 4) void trace_kernel(
    const float* __restrict__ pre, const float* __restrict__ post,
    unsigned short* __restrict__ Abuf, unsigned short* __restrict__ Bbuf,
    float d_plus, float d_x, float d_minus, float d_y)
{
  // blockIdx.x: [0, 2*32*32): nb (32) | b (32) | side (2)
  int nb   = blockIdx.x & 31;
  int b    = (blockIdx.x >> 5) & 31;
  int side = blockIdx.x >> 10;
  int tid  = threadIdx.x;
  int seg  = tid >> 5;                             // [0,8)
  int nl   = tid & 31;
  int n    = nb * 32 + nl;

  const float* sp = (side ? post : pre) + (size_t)b * Tt * Nn + n;
  float da = side ? d_minus : d_plus;
  float db = side ? d_y     : d_x;
  float c1 = side ? -A_MINUS : A_PLUS;
  float c2 = side ? -A_TM    : A_TP;
  unsigned short* dbuf = side ? Bbuf : Abuf;
  int sw = (nl >> 1) & 3;                          // == (n>>1)&3 (nb*32 = 0 mod 8)
  int t0 = seg * SLEN;

  // 32KB staging: op[seg][dX][nl][32] — region (seg,dX) = 2KB contiguous in
  // the global image for the CURRENT ktile round (swizzle applied at write).
  __shared__ __align__(16) unsigned short op[SEG][2][32][32];
  float* lds1 = (float*)&op[0][0][0][0];           // scan scratch alias (1KB)
  float* lds2 = lds1 + SEG * 32;                   // (+1KB)

  // --- Phase A: 64 pinned loads (asm: non-rematerializable), then wait ---
  float s[SLEN];
#pragma unroll
  for (int j = 0; j < SLEN; ++j) {
    const float* ga = sp + (size_t)(t0 + j) * Nn;
    asm volatile("global_load_dword %0, %1, off" : "=v"(s[j]) : "v"(ga));
  }
  asm volatile("s_waitcnt vmcnt(0)" ::: "memory");
  __builtin_amdgcn_sched_barrier(0);               // no use hoisted above the wait

  float l1 = 0.f, l2 = 0.f;
#pragma unroll
  for (int j = 0; j < SLEN; ++j) {
    l1 = l1 * da + s[j];                           // combined step: decay then add
    l2 = l2 * db + s[j];
  }

  // d^64 via 6 squarings
  float dL1 = da, dL2 = db;
#pragma unroll
  for (int q = 0; q < 6; ++q) { dL1 *= dL1; dL2 *= dL2; }

  // --- Exclusive scan over the 8 segments of each chain, via LDS ---
  lds1[seg * 32 + nl] = l1; lds2[seg * 32 + nl] = l2;
  __syncthreads();
  float tr1 = 0.f, tr2 = 0.f;                      // carry entering this segment
#pragma unroll
  for (int m = 0; m < SEG - 1; ++m) {
    if (m < seg) {
      tr1 = tr1 * dL1 + lds1[m * 32 + nl];
      tr2 = tr2 * dL2 + lds2[m * 32 + nl];
    }
  }
  __syncthreads();                                 // scan scratch dead; staging begins

  int wid = tid >> 6, lane = tid & 63;

  // --- Phase B: two ktile rounds; each consumes 32 t from live registers ---
#pragma unroll
  for (int r = 0; r < 2; ++r) {
#pragma unroll
    for (int g2 = 0; g2 < 2; ++g2) {
      short8 w0[2], w1[2];
#pragma unroll
      for (int j = 0; j < 16; ++j) {
        float sv = s[r * 32 + g2 * 16 + j];
        tr1 *= da; tr2 *= db;                      // decay first
        float tv = c1 * tr1 + c2 * (tr1 * tr2);    // trace factor (pre spike-add)
        unsigned short bs = f2bf(sv);
        unsigned short bt = f2bf(tv);
        unsigned short h0 = side ? bs : bt;        // half0: P / post
        unsigned short h1 = side ? bt : bs;        // half1: pre / -Y
        w0[j >> 3][j & 7] = (short)h0;
        w1[j >> 3][j & 7] = (short)h1;
        tr1 += sv; tr2 += sv;                      // then add spike
      }
#pragma unroll
      for (int i = 0; i < 2; ++i) {
        int slot = g2 * 2 + i;                     // slot within this ktile row
        *(short8*)&op[seg][0][nl][(slot ^ sw) * 8] = w0[i];   // swizzled LDS image
        *(short8*)&op[seg][1][nl][(slot ^ sw) * 8] = w1[i];
      }
    }
    __syncthreads();

    // --- Cooperative coalesced store: 16 regions x 2KB, 1KB per wave-instr ---
    // region rid = seg*2 + dX; ktile index = dX*512 + b*16 + seg*2 + r;
    // global base elems = (ktile*8 + (nb>>2))*4096 + (nb&3)*1024.
    const unsigned short* opb = &op[0][0][0][0];
#pragma unroll
    for (int i = 0; i < 4; ++i) {
      int rid = wid * 4 + i;
      int sg  = rid >> 1;
      int dX  = rid & 1;
      size_t kt = (size_t)(dX * 512 + b * 16 + sg * 2 + r);
      size_t ge = (kt * 8 + (size_t)(nb >> 2)) * 4096 + (size_t)(nb & 3) * 1024;
#pragma unroll
      for (int h = 0; h < 2; ++h) {
        *(short8*)(dbuf + ge + h * 512 + lane * 8) =
            *(const short8*)(opb + (size_t)rid * 1024 + h * 512 + lane * 8);
      }
    }
    if (r == 0) __syncthreads();                   // LDS reused by round 1
  }
}

// ---------------------------------------------------------------------------
// Phase 2: wu = sum_s A^T B over split k-ranges. R6 inner structure (proven)
// + R17 atomic epilogue. R18: SPLITS 8->16. Counter evidence (R17): gemm
// 83us, MfmaUtil 34%, Occupancy 19% — barrier-synchronized staging latency
// with only ~2 blocks/CU of TLP. 1024 blocks -> 3 resident blocks/CU
// (LDS 48KB x 3 = 144 <= 160KB), more cross-block overlap at the barrier.
// (R15's gated splits=16 likely never ran: counters were identical to R14.)
// ---------------------------------------------------------------------------
#define GLL(gp, lp)                                                         \
  __builtin_amdgcn_global_load_lds(                                         \
      (const __attribute__((address_space(1))) unsigned int*)(gp),          \
      (__attribute__((address_space(3))) unsigned int*)(lp), 16, 0, 0)

// s_waitcnt imm (gfx9 encoding): lgkm[11:8]=0xF (no wait), exp[6:4]=0x7,
// vmcnt low4 in [3:0], hi2 in [15:14]=0
#define WAITCNT_VM8 0xF78
#define WAITCNT_VM4 0xF74
#define WAITCNT_VM0 0xF70

__global__ __launch_bounds__(BDIM) void gemm_kernel(
    const unsigned short* __restrict__ Abuf, const unsigned short* __restrict__ Bbuf,
    float* __restrict__ outp, float scale)
{
  __shared__ unsigned short smem[3 * 8192];  // ring of 3 x (A 8KB-elems | B)
  int tid  = threadIdx.x;
  int s    = blockIdx.x & 15;                // split; s%8 -> XCD id round-robin
  int tile = blockIdx.x >> 4;                // [0,64)
  int pt   = tile & 7;
  int qt   = tile >> 3;

  float4v acc[4][4];
#pragma unroll
  for (int i = 0; i < 4; ++i)
#pragma unroll
    for (int j = 0; j < 4; ++j) acc[i][j] = (float4v){0.f, 0.f, 0.f, 0.f};

  int wid = tid >> 6, lane = tid & 63;
  int wr = wid >> 1, wc = wid & 1;
  int rA = wr * 64 + (lane & 15);
  int rB = wc * 64 + (lane & 15);
  // swizzled 16B-slot: lane wants k-group (lane>>4); stored slot is ^((row>>1)&3)
  int kg = (((lane >> 4) ^ ((lane >> 1) & 3)) * 8);

  const unsigned short* ga = Abuf + ((size_t)(s * NKT) * 8 + pt) * 4096 + tid * 8;
  const unsigned short* gb = Bbuf + ((size_t)(s * NKT) * 8 + qt) * 4096 + tid * 8;

  // issue the 4 staging loads for tile kt into ring slot kt%3
#define ISSUE(kt_) do {                                                     \
    unsigned short* sb_ = smem + ((kt_) % 3) * 8192;                        \
    const unsigned short* a_ = ga + (size_t)(kt_) * 8 * 4096;               \
    const unsigned short* b_ = gb + (size_t)(kt_) * 8 * 4096;               \
    GLL(a_,        sb_ + tid * 8);                                          \
    GLL(a_ + 2048, sb_ + 2048 + tid * 8);                                   \
    GLL(b_,        sb_ + 4096 + tid * 8);                                   \
    GLL(b_ + 2048, sb_ + 6144 + tid * 8);                                   \
  } while (0)

  ISSUE(0);
  ISSUE(1);

  for (int kt = 0; kt < NKT; ++kt) {
    if (kt + 2 < NKT) {
      ISSUE(kt + 2);
      __builtin_amdgcn_s_waitcnt(WAITCNT_VM8);   // tile kt landed; kt+1,kt+2 in flight
    } else if (kt + 2 == NKT) {
      __builtin_amdgcn_s_waitcnt(WAITCNT_VM4);   // tile kt landed; kt+1 in flight
    } else {
      __builtin_amdgcn_s_waitcnt(WAITCNT_VM0);   // last tile
    }
    __builtin_amdgcn_s_barrier();                // bare barrier — no vmcnt(0) drain

    const unsigned short* sb = smem + (kt % 3) * 8192;
    short8 af[4], bfv[4];
#pragma unroll
    for (int mi = 0; mi < 4; ++mi)
      af[mi] = *(const short8*)(sb + (rA + mi * 16) * 32 + kg);       // ds_read_b128
#pragma unroll
    for (int ni = 0; ni < 4; ++ni)
      bfv[ni] = *(const short8*)(sb + 4096 + (rB + ni * 16) * 32 + kg);
#pragma unroll
    for (int mi = 0; mi < 4; ++mi)
#pragma unroll
      for (int ni = 0; ni < 4; ++ni)
        acc[mi][ni] = __builtin_amdgcn_mfma_f32_16x16x32_bf16(af[mi], bfv[ni], acc[mi][ni], 0, 0, 0);
  }

  // C/D layout: col = lane&15, row = (lane>>4)*4 + reg.
  // Epilogue: scaled atomic accumulate straight into the output (split-K sum).
#pragma unroll
  for (int mi = 0; mi < 4; ++mi)
#pragma unroll
    for (int r = 0; r < 4; ++r) {
      int row = pt * 128 + wr * 64 + mi * 16 + (lane >> 4) * 4 + r;
#pragma unroll
      for (int ni = 0; ni < 4; ++ni) {
        int col = qt * 128 + wc * 64 + ni * 16 + (lane & 15);
        atomicAdd(&outp[(size_t)row * Nn + col], acc[mi][ni][r] * scale);
      }
    }
#undef ISSUE
}

extern "C" void kernel_launch(void* const* d_in, const int* in_sizes, int n_in,
                              void* d_out, int out_size, void* d_ws, size_t ws_size,
                              hipStream_t stream)
{
  const float* pre  = (const float*)d_in[0];
  const float* post = (const float*)d_in[1];
  float* out = (float*)d_out;
  char* ws = (char*)d_ws;

  size_t sizeAB = (size_t)2 * Bsz * Tt * Nn * 2;   // one operand buffer = 64 MB

  unsigned short* Abuf = (unsigned short*)ws;
  unsigned short* Bbuf = (unsigned short*)(ws + sizeAB);

  float d_plus  = expf(-1.0f / 20.0f);
  float d_x     = expf(-1.0f / 101.0f);
  float d_minus = expf(-1.0f / 20.0f);
  float d_y     = expf(-1.0f / 114.0f);

  trace_kernel<<<2 * Bsz * Nn / 32, BDIM, 0, stream>>>(
      pre, post, Abuf, Bbuf, d_plus, d_x, d_minus, d_y);
  gemm_kernel<<<64 * SPLITS, BDIM, 0, stream>>>(
      Abuf, Bbuf, out, 1.0f / (float)(Bsz * Tt));
}

// Round 13
// 242.976 us; speedup vs baseline: 1.0887x; 1.0887x over previous
//
#include <hip/hip_runtime.h>
#include <cstdint>
#include <cmath>

#define BDIM 256

constexpr int Bsz = 32;
constexpr int Tt  = 512;
constexpr int Nn  = 1024;
constexpr int SEG = 8;     // T split into 8 segments of 64 for the scan (R8)
constexpr int SLEN = 64;
constexpr int SPLITS = 8;  // split-K (16 tested twice: R15 null, R18 regressed)
constexpr int NKT = (2 * Bsz * Tt / 32) / SPLITS;  // 128 ktiles per split
constexpr float A_PLUS  = 0.005f;
constexpr float A_MINUS = 0.00525f;
constexpr float A_TP    = 0.0001f;
constexpr float A_TM    = 0.0001f;

typedef __attribute__((ext_vector_type(8))) short short8;   // 8 bf16 = 4 VGPRs
typedef __attribute__((ext_vector_type(4))) float float4v;  // MFMA acc

__device__ __forceinline__ unsigned short f2bf(float f) {
  // round-to-nearest-even fp32 -> bf16 (values are finite)
  unsigned u = __float_as_uint(f);
  u += 0x7fffu + ((u >> 16) & 1u);
  return (unsigned short)(u >> 16);
}

// ---------------------------------------------------------------------------
// Phase 1: trace recurrences -> bf16 operands. FROZEN at R14 — best measured
// (80-82us across 5 rounds). R9-R16 falsified every Phase-B re-acquisition
// theory (registers/AGPR, LDS-resident, global re-read, cvt_pk packing);
// kernel is phase-structure-bound at ~2.5 blocks/CU.
// ---------------------------------------------------------------------------
__global__ __launch_bounds__(BDIM, 4) void trace_kernel(
    const float* __restrict__ pre, const float* __restrict__ post,
    unsigned short* __restrict__ Abuf, unsigned short* __restrict__ Bbuf,
    float d_plus, float d_x, float d_minus, float d_y)
{
  // blockIdx.x: [0, 2*32*32): nb (32) | b (32) | side (2)
  int nb   = blockIdx.x & 31;
  int b    = (blockIdx.x >> 5) & 31;
  int side = blockIdx.x >> 10;
  int tid  = threadIdx.x;
  int seg  = tid >> 5;                             // [0,8)
  int nl   = tid & 31;
  int n    = nb * 32 + nl;

  const float* sp = (side ? post : pre) + (size_t)b * Tt * Nn + n;
  float da = side ? d_minus : d_plus;
  float db = side ? d_y     : d_x;
  float c1 = side ? -A_MINUS : A_PLUS;
  float c2 = side ? -A_TM    : A_TP;
  unsigned short* dbuf = side ? Bbuf : Abuf;
  int sw = (nl >> 1) & 3;                          // == (n>>1)&3 (nb*32 = 0 mod 8)
  int t0 = seg * SLEN;

  // 32KB staging: op[seg][dX][nl][32] — region (seg,dX) = 2KB contiguous in
  // the global image for the CURRENT ktile round (swizzle applied at write).
  __shared__ __align__(16) unsigned short op[SEG][2][32][32];
  float* lds1 = (float*)&op[0][0][0][0];           // scan scratch alias (1KB)
  float* lds2 = lds1 + SEG * 32;                   // (+1KB)

  // --- Phase A: 64 pinned loads (asm: non-rematerializable), then wait ---
  float s[SLEN];
#pragma unroll
  for (int j = 0; j < SLEN; ++j) {
    const float* ga = sp + (size_t)(t0 + j) * Nn;
    asm volatile("global_load_dword %0, %1, off" : "=v"(s[j]) : "v"(ga));
  }
  asm volatile("s_waitcnt vmcnt(0)" ::: "memory");
  __builtin_amdgcn_sched_barrier(0);               // no use hoisted above the wait

  float l1 = 0.f, l2 = 0.f;
#pragma unroll
  for (int j = 0; j < SLEN; ++j) {
    l1 = l1 * da + s[j];                           // combined step: decay then add
    l2 = l2 * db + s[j];
  }

  // d^64 via 6 squarings
  float dL1 = da, dL2 = db;
#pragma unroll
  for (int q = 0; q < 6; ++q) { dL1 *= dL1; dL2 *= dL2; }

  // --- Exclusive scan over the 8 segments of each chain, via LDS ---
  lds1[seg * 32 + nl] = l1; lds2[seg * 32 + nl] = l2;
  __syncthreads();
  float tr1 = 0.f, tr2 = 0.f;                      // carry entering this segment
#pragma unroll
  for (int m = 0; m < SEG - 1; ++m) {
    if (m < seg) {
      tr1 = tr1 * dL1 + lds1[m * 32 + nl];
      tr2 = tr2 * dL2 + lds2[m * 32 + nl];
    }
  }
  __syncthreads();                                 // scan scratch dead; staging begins

  int wid = tid >> 6, lane = tid & 63;

  // --- Phase B: two ktile rounds; each consumes 32 t from live registers ---
#pragma unroll
  for (int r = 0; r < 2; ++r) {
#pragma unroll
    for (int g2 = 0; g2 < 2; ++g2) {
      short8 w0[2], w1[2];
#pragma unroll
      for (int j = 0; j < 16; ++j) {
        float sv = s[r * 32 + g2 * 16 + j];
        tr1 *= da; tr2 *= db;                      // decay first
        float tv = c1 * tr1 + c2 * (tr1 * tr2);    // trace factor (pre spike-add)
        unsigned short bs = f2bf(sv);
        unsigned short bt = f2bf(tv);
        unsigned short h0 = side ? bs : bt;        // half0: P / post
        unsigned short h1 = side ? bt : bs;        // half1: pre / -Y
        w0[j >> 3][j & 7] = (short)h0;
        w1[j >> 3][j & 7] = (short)h1;
        tr1 += sv; tr2 += sv;                      // then add spike
      }
#pragma unroll
      for (int i = 0; i < 2; ++i) {
        int slot = g2 * 2 + i;                     // slot within this ktile row
        *(short8*)&op[seg][0][nl][(slot ^ sw) * 8] = w0[i];   // swizzled LDS image
        *(short8*)&op[seg][1][nl][(slot ^ sw) * 8] = w1[i];
      }
    }
    __syncthreads();

    // --- Cooperative coalesced store: 16 regions x 2KB, 1KB per wave-instr ---
    // region rid = seg*2 + dX; ktile index = dX*512 + b*16 + seg*2 + r;
    // global base elems = (ktile*8 + (nb>>2))*4096 + (nb&3)*1024.
    const unsigned short* opb = &op[0][0][0][0];
#pragma unroll
    for (int i = 0; i < 4; ++i) {
      int rid = wid * 4 + i;
      int sg  = rid >> 1;
      int dX  = rid & 1;
      size_t kt = (size_t)(dX * 512 + b * 16 + sg * 2 + r);
      size_t ge = (kt * 8 + (size_t)(nb >> 2)) * 4096 + (size_t)(nb & 3) * 1024;
#pragma unroll
      for (int h = 0; h < 2; ++h) {
        *(short8*)(dbuf + ge + h * 512 + lane * 8) =
            *(const short8*)(opb + (size_t)rid * 1024 + h * 512 + lane * 8);
      }
    }
    if (r == 0) __syncthreads();                   // LDS reused by round 1
  }
}

// ---------------------------------------------------------------------------
// Phase 2: wu_partial[s] = A^T * B over this split's k-range.
// R6 structure — best measured (~75-83us, 830TF, MfmaUtil 34% = this
// structure's ceiling): 3-stage LDS ring, loads in flight across a bare
// s_barrier, fine-grained s_waitcnt vmcnt (never a full drain). XCD-aware
// flat grid (s = blk&7). Atomic-epilogue (R17: +5us) and splits=16
// (R18: +21us) both tested and reverted.
// ---------------------------------------------------------------------------
#define GLL(gp, lp)                                                         \
  __builtin_amdgcn_global_load_lds(                                         \
      (const __attribute__((address_space(1))) unsigned int*)(gp),          \
      (__attribute__((address_space(3))) unsigned int*)(lp), 16, 0, 0)

// s_waitcnt imm (gfx9 encoding): lgkm[11:8]=0xF (no wait), exp[6:4]=0x7,
// vmcnt low4 in [3:0], hi2 in [15:14]=0
#define WAITCNT_VM8 0xF78
#define WAITCNT_VM4 0xF74
#define WAITCNT_VM0 0xF70

__global__ __launch_bounds__(BDIM) void gemm_kernel(
    const unsigned short* __restrict__ Abuf, const unsigned short* __restrict__ Bbuf,
    float* __restrict__ partials)
{
  __shared__ unsigned short smem[3 * 8192];  // ring of 3 x (A 8KB-elems | B)
  int tid  = threadIdx.x;
  int s    = blockIdx.x & 7;                 // low bits -> XCD id under round-robin
  int tile = blockIdx.x >> 3;                // [0,64)
  int pt   = tile & 7;
  int qt   = tile >> 3;

  float4v acc[4][4];
#pragma unroll
  for (int i = 0; i < 4; ++i)
#pragma unroll
    for (int j = 0; j < 4; ++j) acc[i][j] = (float4v){0.f, 0.f, 0.f, 0.f};

  int wid = tid >> 6, lane = tid & 63;
  int wr = wid >> 1, wc = wid & 1;
  int rA = wr * 64 + (lane & 15);
  int rB = wc * 64 + (lane & 15);
  // swizzled 16B-slot: lane wants k-group (lane>>4); stored slot is ^((row>>1)&3)
  int kg = (((lane >> 4) ^ ((lane >> 1) & 3)) * 8);

  const unsigned short* ga = Abuf + ((size_t)(s * NKT) * 8 + pt) * 4096 + tid * 8;
  const unsigned short* gb = Bbuf + ((size_t)(s * NKT) * 8 + qt) * 4096 + tid * 8;

  // issue the 4 staging loads for tile kt into ring slot kt%3
#define ISSUE(kt_) do {                                                     \
    unsigned short* sb_ = smem + ((kt_) % 3) * 8192;                        \
    const unsigned short* a_ = ga + (size_t)(kt_) * 8 * 4096;               \
    const unsigned short* b_ = gb + (size_t)(kt_) * 8 * 4096;               \
    GLL(a_,        sb_ + tid * 8);                                          \
    GLL(a_ + 2048, sb_ + 2048 + tid * 8);                                   \
    GLL(b_,        sb_ + 4096 + tid * 8);                                   \
    GLL(b_ + 2048, sb_ + 6144 + tid * 8);                                   \
  } while (0)

  ISSUE(0);
  ISSUE(1);

  for (int kt = 0; kt < NKT; ++kt) {
    if (kt + 2 < NKT) {
      ISSUE(kt + 2);
      __builtin_amdgcn_s_waitcnt(WAITCNT_VM8);   // tile kt landed; kt+1,kt+2 in flight
    } else if (kt + 2 == NKT) {
      __builtin_amdgcn_s_waitcnt(WAITCNT_VM4);   // tile kt landed; kt+1 in flight
    } else {
      __builtin_amdgcn_s_waitcnt(WAITCNT_VM0);   // last tile
    }
    __builtin_amdgcn_s_barrier();                // bare barrier — no vmcnt(0) drain

    const unsigned short* sb = smem + (kt % 3) * 8192;
    short8 af[4], bfv[4];
#pragma unroll
    for (int mi = 0; mi < 4; ++mi)
      af[mi] = *(const short8*)(sb + (rA + mi * 16) * 32 + kg);       // ds_read_b128
#pragma unroll
    for (int ni = 0; ni < 4; ++ni)
      bfv[ni] = *(const short8*)(sb + 4096 + (rB + ni * 16) * 32 + kg);
#pragma unroll
    for (int mi = 0; mi < 4; ++mi)
#pragma unroll
      for (int ni = 0; ni < 4; ++ni)
        acc[mi][ni] = __builtin_amdgcn_mfma_f32_16x16x32_bf16(af[mi], bfv[ni], acc[mi][ni], 0, 0, 0);
  }

  // C/D layout: col = lane&15, row = (lane>>4)*4 + reg.  Single chunk: plain store.
  float* po = partials + (size_t)s * Nn * Nn;
#pragma unroll
  for (int mi = 0; mi < 4; ++mi)
#pragma unroll
    for (int r = 0; r < 4; ++r) {
      int row = pt * 128 + wr * 64 + mi * 16 + (lane >> 4) * 4 + r;
#pragma unroll
      for (int ni = 0; ni < 4; ++ni) {
        int col = qt * 128 + wc * 64 + ni * 16 + (lane & 15);
        po[(size_t)row * Nn + col] = acc[mi][ni][r];
      }
    }
#undef ISSUE
}

// ---------------------------------------------------------------------------
// Phase 3: reduce split-K partials (float4), apply 1/(B*T)
// ---------------------------------------------------------------------------
__global__ __launch_bounds__(BDIM) void reduce_kernel(
    const float4v* __restrict__ partials, float4v* __restrict__ out, int S, float scale)
{
  size_t i = (size_t)blockIdx.x * BDIM + threadIdx.x;
  float4v v = (float4v){0.f, 0.f, 0.f, 0.f};
  for (int s = 0; s < S; ++s) v += partials[(size_t)s * (Nn * Nn / 4) + i];
  out[i] = v * scale;
}

extern "C" void kernel_launch(void* const* d_in, const int* in_sizes, int n_in,
                              void* d_out, int out_size, void* d_ws, size_t ws_size,
                              hipStream_t stream)
{
  const float* pre  = (const float*)d_in[0];
  const float* post = (const float*)d_in[1];
  float4v* out = (float4v*)d_out;
  char* ws = (char*)d_ws;

  size_t sizeAB = (size_t)2 * Bsz * Tt * Nn * 2;   // one operand buffer = 64 MB

  float* partials = (float*)ws;
  unsigned short* Abuf = (unsigned short*)(ws + (size_t)SPLITS * Nn * Nn * 4);
  unsigned short* Bbuf = (unsigned short*)(ws + (size_t)SPLITS * Nn * Nn * 4 + sizeAB);

  float d_plus  = expf(-1.0f / 20.0f);
  float d_x     = expf(-1.0f / 101.0f);
  float d_minus = expf(-1.0f / 20.0f);
  float d_y     = expf(-1.0f / 114.0f);

  trace_kernel<<<2 * Bsz * Nn / 32, BDIM, 0, stream>>>(
      pre, post, Abuf, Bbuf, d_plus, d_x, d_minus, d_y);
  gemm_kernel<<<64 * SPLITS, BDIM, 0, stream>>>(Abuf, Bbuf, partials);
  reduce_kernel<<<(Nn * Nn / 4) / BDIM, BDIM, 0, stream>>>(
      (const float4v*)partials, out, SPLITS, 1.0f / (float)(Bsz * Tt));
}